// Round 9
// baseline (134.640 us; speedup 1.0000x reference)
//
#include <hip/hip_runtime.h>

#define B_SZ 64
#define S_SZ 2048
#define RNN 1024
#define ATT 512
#define NCHUNK 32
#define CHUNK_S (S_SZ / NCHUNK)   // 64
#define KSPL 2                    // k-split halves for the h-GEMM

// ws layout in floats:
//   att_h_part: [KSPL][B][ATT]      off 0         (65536)
//   partials  : [B][NCHUNK][RNN]    off 65536     (2097152)
//   usum      : [B][NCHUNK]         off 2162688   (2048)
#define OFF_ATTHP  0
#define OFF_PART   65536
#define OFF_USUM   2162688

// tanh(x) = 1 - 2/(1 + 2^(x * 2/ln2))
__device__ __forceinline__ float fast_tanh(float x) {
    float t = __builtin_exp2f(x * 2.885390082f);
    return 1.0f - 2.0f * __builtin_amdgcn_rcpf(t + 1.0f);
}

// --- Kernel 0: att_h_part[ks][b][j] = h[b, ks*512..+512) . W_h[j, same) ---
// grid (4, KSPL, B), block 128; 4 independent accumulators
__global__ __launch_bounds__(128) void k_atth(const float* __restrict__ h,
                                              const float* __restrict__ Wh,
                                              float* __restrict__ att_h_part) {
    int b  = blockIdx.z;
    int ks = blockIdx.y;
    int j  = blockIdx.x * 128 + threadIdx.x;   // 0..511
    int kbase = ks * (RNN / KSPL);

    __shared__ float hs[RNN / KSPL];           // 512 floats
    for (int i = threadIdx.x; i < RNN / KSPL; i += 128)
        hs[i] = h[(size_t)b * RNN + kbase + i];
    __syncthreads();

    const float4* w4 = (const float4*)(Wh + (size_t)j * RNN + kbase);
    const float4* h4 = (const float4*)hs;
    float a0 = 0.f, a1 = 0.f, a2 = 0.f, a3 = 0.f;
    #pragma unroll 4
    for (int k = 0; k < (RNN / KSPL) / 4; k += 4) {
        float4 w, hv;
        w = w4[k + 0]; hv = h4[k + 0];
        a0 += w.x * hv.x + w.y * hv.y + w.z * hv.z + w.w * hv.w;
        w = w4[k + 1]; hv = h4[k + 1];
        a1 += w.x * hv.x + w.y * hv.y + w.z * hv.z + w.w * hv.w;
        w = w4[k + 2]; hv = h4[k + 2];
        a2 += w.x * hv.x + w.y * hv.y + w.z * hv.z + w.w * hv.w;
        w = w4[k + 3]; hv = h4[k + 3];
        a3 += w.x * hv.x + w.y * hv.y + w.z * hv.z + w.w * hv.w;
    }
    att_h_part[((size_t)ks * B_SZ + b) * ATT + j] = (a0 + a1) + (a2 + a3);
}

// --- Fused, software-pipelined: 4 tiles of 16 compacted slots.
//   Region st: {scores(tile st+1)} + {gather(tile st)} ; one barrier per tile.
// grid (NCHUNK, B), block 256 = 4 waves
__global__ __launch_bounds__(256, 8) void k_fused(const float* __restrict__ p,
                                                  const float* __restrict__ att_h_part,
                                                  const float* __restrict__ bh,
                                                  const float* __restrict__ w_a,
                                                  const float* __restrict__ b_a,
                                                  const int* __restrict__ mask,
                                                  const float* __restrict__ feats,
                                                  float* __restrict__ partials,
                                                  float* __restrict__ usum) {
    int c = blockIdx.x;
    int b = blockIdx.y;
    int t = threadIdx.x;
    int s0 = c * CHUNK_S;

    __shared__ float ah[ATT];
    __shared__ float wa[ATT];
    __shared__ __align__(16) float u_c[CHUNK_S];    // zero beyond nact
    __shared__ __align__(16) int   active[CHUNK_S]; // compacted rows + dummy 0s
    __shared__ int   nact_s;

    const float* ph0 = att_h_part + (size_t)b * ATT;
    const float* ph1 = att_h_part + ((size_t)B_SZ + b) * ATT;
    for (int i = t; i < ATT; i += 256) {
        ah[i] = ph0[i] + ph1[i] + bh[i];
        wa[i] = w_a[i];
    }
    if (t < CHUNK_S) {                 // exactly wave 0; t == lane
        u_c[t] = 0.f;
        int m = mask[(size_t)b * S_SZ + s0 + t];
        unsigned long long bal = __ballot(m != 0);
        int na = (int)__popcll(bal);
        unsigned long long below = (1ULL << (unsigned)t) - 1ULL;
        if (m) {
            active[__popcll(bal & below)] = t;
        } else {
            active[na + __popcll((~bal) & below)] = 0;   // dummy slot, weight 0
        }
        if (t == 0) nact_s = na;
    }
    __syncthreads();
    int nact = nact_s;
    int n16 = (nact + 15) & ~15;
    int n_tiles = n16 >> 4;            // 0..4

    int wave = t >> 6;
    int lane = t & 63;
    float ba = b_a[0];

    const float4* ah4 = (const float4*)ah;
    const float4* wa4 = (const float4*)wa;
    float4 a0 = ah4[lane];
    float4 a1 = ah4[64 + lane];
    float4 w0 = wa4[lane];
    float4 w1 = wa4[64 + lane];

    const float4* pbase = (const float4*)(p + ((size_t)b * S_SZ + s0) * ATT);
    const float4* f4 = (const float4*)(feats + ((size_t)b * S_SZ + s0) * RNN);
    const int4*   act4 = (const int4*)active;
    const float4* uc4  = (const float4*)u_c;
    float4 acc = {0.f, 0.f, 0.f, 0.f};

    // ---- scores for one 16-slot tile: 4 rows per wave, 2x2 ----
    #define SCORE_TILE(TILE)                                                    \
    {                                                                           \
        int base_ = ((TILE) << 4) + wave * 4;                                   \
        _Pragma("unroll")                                                       \
        for (int i_ = 0; i_ < 2; ++i_) {                                        \
            int kA_ = base_ + i_ * 2, kB_ = kA_ + 1;                            \
            int slA_ = active[kA_], slB_ = active[kB_];                         \
            const float4* pA_ = pbase + (size_t)slA_ * 128;                     \
            const float4* pB_ = pbase + (size_t)slB_ * 128;                     \
            float4 xa0_ = pA_[lane];                                            \
            float4 xa1_ = pA_[64 + lane];                                       \
            float4 xb0_ = pB_[lane];                                            \
            float4 xb1_ = pB_[64 + lane];                                       \
            float pa_, pb_;                                                     \
            pa_  = w0.x * fast_tanh(xa0_.x + a0.x);                             \
            pa_ += w0.y * fast_tanh(xa0_.y + a0.y);                             \
            pa_ += w0.z * fast_tanh(xa0_.z + a0.z);                             \
            pa_ += w0.w * fast_tanh(xa0_.w + a0.w);                             \
            pa_ += w1.x * fast_tanh(xa1_.x + a1.x);                             \
            pa_ += w1.y * fast_tanh(xa1_.y + a1.y);                             \
            pa_ += w1.z * fast_tanh(xa1_.z + a1.z);                             \
            pa_ += w1.w * fast_tanh(xa1_.w + a1.w);                             \
            pb_  = w0.x * fast_tanh(xb0_.x + a0.x);                             \
            pb_ += w0.y * fast_tanh(xb0_.y + a0.y);                             \
            pb_ += w0.z * fast_tanh(xb0_.z + a0.z);                             \
            pb_ += w0.w * fast_tanh(xb0_.w + a0.w);                             \
            pb_ += w1.x * fast_tanh(xb1_.x + a1.x);                             \
            pb_ += w1.y * fast_tanh(xb1_.y + a1.y);                             \
            pb_ += w1.z * fast_tanh(xb1_.z + a1.z);                             \
            pb_ += w1.w * fast_tanh(xb1_.w + a1.w);                             \
            _Pragma("unroll")                                                   \
            for (int off_ = 32; off_ > 0; off_ >>= 1) {                         \
                pa_ += __shfl_xor(pa_, off_, 64);                               \
                pb_ += __shfl_xor(pb_, off_, 64);                               \
            }                                                                   \
            if (lane == 0) {                                                    \
                if (kA_ < nact) u_c[kA_] = __builtin_expf(fminf(pa_ + ba, 80.f)); \
                if (kB_ < nact) u_c[kB_] = __builtin_expf(fminf(pb_ + ba, 80.f)); \
            }                                                                   \
        }                                                                       \
    }

    // ---- gather one 16-slot tile (2 x 8-deep) ----
    #define GATHER_TILE(TILE)                                                   \
    {                                                                           \
        _Pragma("unroll")                                                       \
        for (int kk_ = 0; kk_ < 2; ++kk_) {                                     \
            int q_ = ((TILE) << 2) + kk_ * 2;                                   \
            int4  r0_ = act4[q_];                                               \
            int4  r1_ = act4[q_ + 1];                                           \
            float4 g0_ = uc4[q_];                                               \
            float4 g1_ = uc4[q_ + 1];                                           \
            float4 v0_ = f4[(size_t)r0_.x * 256 + t];                           \
            float4 v1_ = f4[(size_t)r0_.y * 256 + t];                           \
            float4 v2_ = f4[(size_t)r0_.z * 256 + t];                           \
            float4 v3_ = f4[(size_t)r0_.w * 256 + t];                           \
            float4 v4_ = f4[(size_t)r1_.x * 256 + t];                           \
            float4 v5_ = f4[(size_t)r1_.y * 256 + t];                           \
            float4 v6_ = f4[(size_t)r1_.z * 256 + t];                           \
            float4 v7_ = f4[(size_t)r1_.w * 256 + t];                           \
            acc.x += g0_.x * v0_.x; acc.y += g0_.x * v0_.y; acc.z += g0_.x * v0_.z; acc.w += g0_.x * v0_.w; \
            acc.x += g0_.y * v1_.x; acc.y += g0_.y * v1_.y; acc.z += g0_.y * v1_.z; acc.w += g0_.y * v1_.w; \
            acc.x += g0_.z * v2_.x; acc.y += g0_.z * v2_.y; acc.z += g0_.z * v2_.z; acc.w += g0_.z * v2_.w; \
            acc.x += g0_.w * v3_.x; acc.y += g0_.w * v3_.y; acc.z += g0_.w * v3_.z; acc.w += g0_.w * v3_.w; \
            acc.x += g1_.x * v4_.x; acc.y += g1_.x * v4_.y; acc.z += g1_.x * v4_.z; acc.w += g1_.x * v4_.w; \
            acc.x += g1_.y * v5_.x; acc.y += g1_.y * v5_.y; acc.z += g1_.y * v5_.z; acc.w += g1_.y * v5_.w; \
            acc.x += g1_.z * v6_.x; acc.y += g1_.z * v6_.y; acc.z += g1_.z * v6_.z; acc.w += g1_.z * v6_.w; \
            acc.x += g1_.w * v7_.x; acc.y += g1_.w * v7_.y; acc.z += g1_.w * v7_.z; acc.w += g1_.w * v7_.w; \
        }                                                                       \
    }

    // pipeline: prologue scores(0); region st: scores(st+1) + gather(st); barrier
    if (n_tiles > 0) {
        SCORE_TILE(0);
        __syncthreads();
        for (int st = 0; st < n_tiles; ++st) {
            if (st + 1 < n_tiles) SCORE_TILE(st + 1);
            GATHER_TILE(st);
            __syncthreads();
        }
    }

    ((float4*)partials)[((size_t)b * NCHUNK + c) * 256 + t] = acc;

    if (wave == 0) {
        float s = u_c[lane];   // zeros beyond nact
        #pragma unroll
        for (int off = 32; off > 0; off >>= 1)
            s += __shfl_xor(s, off, 64);
        if (lane == 0) usum[(size_t)b * NCHUNK + c] = s;
    }
}

// --- Reduce: out[b,j] = (sum_c partials[b,c,j]) / (sum_c usum[b,c]) ---
// grid (RNN/256, B), block 256
__global__ __launch_bounds__(256) void k_reduce(const float* __restrict__ partials,
                                                const float* __restrict__ usum,
                                                float* __restrict__ out) {
    int b = blockIdx.y;
    int j = blockIdx.x * 256 + threadIdx.x;

    float tot = 0.f;
    #pragma unroll
    for (int c = 0; c < NCHUNK; ++c)
        tot += usum[(size_t)b * NCHUNK + c];   // block-uniform -> scalar loads

    float acc = 0.f;
    #pragma unroll 8
    for (int c = 0; c < NCHUNK; ++c)
        acc += partials[((size_t)b * NCHUNK + c) * RNN + j];

    out[(size_t)b * RNN + j] = acc / tot;
}

extern "C" void kernel_launch(void* const* d_in, const int* in_sizes, int n_in,
                              void* d_out, int out_size, void* d_ws, size_t ws_size,
                              hipStream_t stream) {
    const float* h         = (const float*)d_in[0];
    const float* att_feats = (const float*)d_in[1];
    const float* p_att     = (const float*)d_in[2];
    const int*   att_masks = (const int*)d_in[3];
    const float* W_h       = (const float*)d_in[4];
    const float* b_h       = (const float*)d_in[5];
    const float* w_a       = (const float*)d_in[6];
    const float* b_a       = (const float*)d_in[7];
    float* out = (float*)d_out;

    float* wsf = (float*)d_ws;
    float* att_h_part = wsf + OFF_ATTHP;
    float* partials   = wsf + OFF_PART;
    float* usum       = wsf + OFF_USUM;

    k_atth<<<dim3(4, KSPL, B_SZ), 128, 0, stream>>>(h, W_h, att_h_part);
    k_fused<<<dim3(NCHUNK, B_SZ), 256, 0, stream>>>(p_att, att_h_part, b_h, w_a, b_a,
                                                    att_masks, att_feats,
                                                    partials, usum);
    k_reduce<<<dim3(RNN / 256, B_SZ), 256, 0, stream>>>(partials, usum, out);
}

// Round 10
// 99.922 us; speedup vs baseline: 1.3474x; 1.3474x over previous
//
#include <hip/hip_runtime.h>

#define B_SZ 64
#define S_SZ 2048
#define RNN 1024
#define ATT 512
#define NCHUNK 32
#define CHUNK_S 64
#define KSPL 2

// ws layout in floats:
//   att_h_part: [KSPL][B][ATT]   off 0       (65536)
//   u         : [B][S]           off 65536   (131072)  dense masked exp-scores
#define OFF_ATTHP 0
#define OFF_U     65536

// tanh(x) = 1 - 2/(1 + 2^(x * 2/ln2))
__device__ __forceinline__ float fast_tanh(float x) {
    float t = __builtin_exp2f(x * 2.885390082f);
    return 1.0f - 2.0f * __builtin_amdgcn_rcpf(t + 1.0f);
}

// --- Kernel 0: att_h_part[ks][b][j] = h[b, ks*512..+512) . W_h[j, same) ---
// grid (4, KSPL, B), block 128; 4 independent accumulators  (unchanged, proven)
__global__ __launch_bounds__(128) void k_atth(const float* __restrict__ h,
                                              const float* __restrict__ Wh,
                                              float* __restrict__ att_h_part) {
    int b  = blockIdx.z;
    int ks = blockIdx.y;
    int j  = blockIdx.x * 128 + threadIdx.x;   // 0..511
    int kbase = ks * (RNN / KSPL);

    __shared__ float hs[RNN / KSPL];           // 512 floats
    for (int i = threadIdx.x; i < RNN / KSPL; i += 128)
        hs[i] = h[(size_t)b * RNN + kbase + i];
    __syncthreads();

    const float4* w4 = (const float4*)(Wh + (size_t)j * RNN + kbase);
    const float4* h4 = (const float4*)hs;
    float a0 = 0.f, a1 = 0.f, a2 = 0.f, a3 = 0.f;
    #pragma unroll 4
    for (int k = 0; k < (RNN / KSPL) / 4; k += 4) {
        float4 w, hv;
        w = w4[k + 0]; hv = h4[k + 0];
        a0 += w.x * hv.x + w.y * hv.y + w.z * hv.z + w.w * hv.w;
        w = w4[k + 1]; hv = h4[k + 1];
        a1 += w.x * hv.x + w.y * hv.y + w.z * hv.z + w.w * hv.w;
        w = w4[k + 2]; hv = h4[k + 2];
        a2 += w.x * hv.x + w.y * hv.y + w.z * hv.z + w.w * hv.w;
        w = w4[k + 3]; hv = h4[k + 3];
        a3 += w.x * hv.x + w.y * hv.y + w.z * hv.z + w.w * hv.w;
    }
    att_h_part[((size_t)ks * B_SZ + b) * ATT + j] = (a0 + a1) + (a2 + a3);
}

// --- Scores: u[b,s] = mask ? exp(w_a . tanh(p[b,s,:]+att_h[b,:]) + b_a) : 0 ---
// R6's proven phase-1 loop, mask-compacted; writes dense u. grid (32,B), 256 thr
__global__ __launch_bounds__(256, 8) void k_scores(const float* __restrict__ p,
                                                   const float* __restrict__ att_h_part,
                                                   const float* __restrict__ bh,
                                                   const float* __restrict__ w_a,
                                                   const float* __restrict__ b_a,
                                                   const int* __restrict__ mask,
                                                   float* __restrict__ u_g) {
    int c = blockIdx.x;
    int b = blockIdx.y;
    int t = threadIdx.x;
    int s0 = c * CHUNK_S;

    __shared__ float ah[ATT];
    __shared__ float wa[ATT];
    __shared__ float u_d[CHUNK_S];     // dense per-chunk weights (0 = masked)
    __shared__ int   active[CHUNK_S];
    __shared__ int   nact_s;

    const float* ph0 = att_h_part + (size_t)b * ATT;
    const float* ph1 = att_h_part + ((size_t)B_SZ + b) * ATT;
    for (int i = t; i < ATT; i += 256) {
        ah[i] = ph0[i] + ph1[i] + bh[i];
        wa[i] = w_a[i];
    }
    if (t < CHUNK_S) {                 // exactly wave 0
        u_d[t] = 0.f;
        int m = mask[(size_t)b * S_SZ + s0 + t];
        unsigned long long bal = __ballot(m != 0);
        int rank = __popcll(bal & ((1ULL << (unsigned)t) - 1ULL));
        if (m) active[rank] = t;
        if (t == 0) nact_s = (int)__popcll(bal);
    }
    __syncthreads();
    int nact = nact_s;

    int wave = t >> 6;
    int lane = t & 63;
    float ba = b_a[0];

    const float4* ah4 = (const float4*)ah;
    const float4* wa4 = (const float4*)wa;
    float4 a0 = ah4[lane];
    float4 a1 = ah4[64 + lane];
    float4 w0 = wa4[lane];
    float4 w1 = wa4[64 + lane];

    const float4* pbase = (const float4*)(p + ((size_t)b * S_SZ + s0) * ATT);
    for (int k = wave; k < nact; k += 4) {
        int sl = active[k];
        const float4* p4 = pbase + (size_t)sl * 128;
        float4 x0 = p4[lane];
        float4 x1 = p4[64 + lane];

        float part;
        part  = w0.x * fast_tanh(x0.x + a0.x);
        part += w0.y * fast_tanh(x0.y + a0.y);
        part += w0.z * fast_tanh(x0.z + a0.z);
        part += w0.w * fast_tanh(x0.w + a0.w);
        part += w1.x * fast_tanh(x1.x + a1.x);
        part += w1.y * fast_tanh(x1.y + a1.y);
        part += w1.z * fast_tanh(x1.z + a1.z);
        part += w1.w * fast_tanh(x1.w + a1.w);

        #pragma unroll
        for (int off = 32; off > 0; off >>= 1)
            part += __shfl_xor(part, off, 64);

        if (lane == 0)
            u_d[sl] = __builtin_expf(fminf(part + ba, 80.f));
    }
    __syncthreads();

    if (t < CHUNK_S)
        u_g[(size_t)b * S_SZ + s0 + t] = u_d[t];
}

// --- Gather: out[b, js*256..+256) = (sum_active u[s]*feats[b,s,cols]) / sum u ---
// grid (4, B), block 512 = 8 waves; block-local deterministic compaction of u[b,:]
__global__ __launch_bounds__(512, 2) void k_gather(const float* __restrict__ feats,
                                                   const float* __restrict__ u_g,
                                                   float* __restrict__ out) {
    int js = blockIdx.x;               // col slice [js*256, +256)
    int b  = blockIdx.y;
    int t  = threadIdx.x;
    int wave = t >> 6, lane = t & 63;

    __shared__ __align__(16) float          cw[2112];    // compact weights (padded)
    __shared__ __align__(16) unsigned short crow[2112];  // compact row idx (padded)
    __shared__ int   counts[32];
    __shared__ int   offs[32];
    __shared__ float wsum[8];
    __shared__ __align__(16) float red[8 * 256];         // cross-wave reduce
    __shared__ int   ntot_s, n64_s;
    __shared__ float inv_s;

    // pass 1: per-64-chunk ballots + counts + partial usum (wave w owns chunks 4w..4w+3)
    float u_r[4];
    unsigned long long bal_r[4];
    float psum = 0.f;
    #pragma unroll
    for (int r = 0; r < 4; ++r) {
        int chunk = wave * 4 + r;
        u_r[r] = u_g[(size_t)b * S_SZ + chunk * 64 + lane];
        psum += u_r[r];
        bal_r[r] = __ballot(u_r[r] > 0.f);
        if (lane == 0) counts[chunk] = (int)__popcll(bal_r[r]);
    }
    #pragma unroll
    for (int off = 32; off > 0; off >>= 1)
        psum += __shfl_xor(psum, off, 64);
    if (lane == 0) wsum[wave] = psum;
    __syncthreads();

    if (t == 0) {
        int o = 0;
        #pragma unroll
        for (int c2 = 0; c2 < 32; ++c2) { offs[c2] = o; o += counts[c2]; }
        ntot_s = o;
        n64_s = (o + 63) & ~63;
        float us = ((wsum[0] + wsum[1]) + (wsum[2] + wsum[3]))
                 + ((wsum[4] + wsum[5]) + (wsum[6] + wsum[7]));
        inv_s = 1.f / us;
    }
    __syncthreads();
    int ntot = ntot_s, n64 = n64_s;

    // pad tail so every 8-group is valid
    for (int k = ntot + t; k < n64; k += 512) { crow[k] = 0; cw[k] = 0.f; }
    // pass 2: deterministic scatter of compact entries
    #pragma unroll
    for (int r = 0; r < 4; ++r) {
        int chunk = wave * 4 + r;
        if (u_r[r] > 0.f) {
            int rank = (int)__popcll(bal_r[r] & ((1ULL << (unsigned)lane) - 1ULL));
            int pos = offs[chunk] + rank;
            crow[pos] = (unsigned short)(chunk * 64 + lane);
            cw[pos]   = u_r[r];
        }
    }
    __syncthreads();

    // gather: wave w handles 8-groups k0 = w*8 + 64*i; lane covers 4 cols (float4)
    const float4* fb = (const float4*)(feats + (size_t)b * S_SZ * RNN);
    int colb = js * 64 + lane;                 // float4-index within a row
    const uint4*  crow4 = (const uint4*)crow;  // 8 u16 per uint4
    const float4* cw4   = (const float4*)cw;
    float4 acc = {0.f, 0.f, 0.f, 0.f};
    for (int k0 = wave * 8; k0 < n64; k0 += 64) {
        uint4  rr = crow4[k0 >> 3];
        float4 ga = cw4[k0 >> 2];
        float4 gb = cw4[(k0 >> 2) + 1];
        int r0 = rr.x & 0xFFFF, r1 = (int)(rr.x >> 16);
        int r2 = rr.y & 0xFFFF, r3 = (int)(rr.y >> 16);
        int r4 = rr.z & 0xFFFF, r5 = (int)(rr.z >> 16);
        int r6 = rr.w & 0xFFFF, r7 = (int)(rr.w >> 16);
        float4 v0 = fb[(size_t)r0 * 256 + colb];
        float4 v1 = fb[(size_t)r1 * 256 + colb];
        float4 v2 = fb[(size_t)r2 * 256 + colb];
        float4 v3 = fb[(size_t)r3 * 256 + colb];
        float4 v4 = fb[(size_t)r4 * 256 + colb];
        float4 v5 = fb[(size_t)r5 * 256 + colb];
        float4 v6 = fb[(size_t)r6 * 256 + colb];
        float4 v7 = fb[(size_t)r7 * 256 + colb];
        acc.x += ga.x * v0.x; acc.y += ga.x * v0.y; acc.z += ga.x * v0.z; acc.w += ga.x * v0.w;
        acc.x += ga.y * v1.x; acc.y += ga.y * v1.y; acc.z += ga.y * v1.z; acc.w += ga.y * v1.w;
        acc.x += ga.z * v2.x; acc.y += ga.z * v2.y; acc.z += ga.z * v2.z; acc.w += ga.z * v2.w;
        acc.x += ga.w * v3.x; acc.y += ga.w * v3.y; acc.z += ga.w * v3.z; acc.w += ga.w * v3.w;
        acc.x += gb.x * v4.x; acc.y += gb.x * v4.y; acc.z += gb.x * v4.z; acc.w += gb.x * v4.w;
        acc.x += gb.y * v5.x; acc.y += gb.y * v5.y; acc.z += gb.y * v5.z; acc.w += gb.y * v5.w;
        acc.x += gb.z * v6.x; acc.y += gb.z * v6.y; acc.z += gb.z * v6.z; acc.w += gb.z * v6.w;
        acc.x += gb.w * v7.x; acc.y += gb.w * v7.y; acc.z += gb.w * v7.z; acc.w += gb.w * v7.w;
    }
    ((float4*)red)[wave * 64 + lane] = acc;
    __syncthreads();

    if (wave == 0) {
        float4 s = {0.f, 0.f, 0.f, 0.f};
        #pragma unroll
        for (int w2 = 0; w2 < 8; ++w2) {          // fixed order -> deterministic
            float4 v = ((const float4*)red)[w2 * 64 + lane];
            s.x += v.x; s.y += v.y; s.z += v.z; s.w += v.w;
        }
        float inv = inv_s;
        float4 o4 = {s.x * inv, s.y * inv, s.z * inv, s.w * inv};
        ((float4*)out)[(size_t)b * 256 + js * 64 + lane] = o4;
    }
}

extern "C" void kernel_launch(void* const* d_in, const int* in_sizes, int n_in,
                              void* d_out, int out_size, void* d_ws, size_t ws_size,
                              hipStream_t stream) {
    const float* h         = (const float*)d_in[0];
    const float* att_feats = (const float*)d_in[1];
    const float* p_att     = (const float*)d_in[2];
    const int*   att_masks = (const int*)d_in[3];
    const float* W_h       = (const float*)d_in[4];
    const float* b_h       = (const float*)d_in[5];
    const float* w_a       = (const float*)d_in[6];
    const float* b_a       = (const float*)d_in[7];
    float* out = (float*)d_out;

    float* wsf = (float*)d_ws;
    float* att_h_part = wsf + OFF_ATTHP;
    float* u_g        = wsf + OFF_U;

    k_atth<<<dim3(4, KSPL, B_SZ), 128, 0, stream>>>(h, W_h, att_h_part);
    k_scores<<<dim3(NCHUNK, B_SZ), 256, 0, stream>>>(p_att, att_h_part, b_h, w_a, b_a,
                                                     att_masks, u_g);
    k_gather<<<dim3(4, B_SZ), 512, 0, stream>>>(att_feats, u_g, out);
}